// Round 1
// baseline (769.083 us; speedup 1.0000x reference)
//
#include <hip/hip_runtime.h>
#include <hip/hip_bf16.h>

typedef __attribute__((ext_vector_type(8))) short sh8;
typedef __attribute__((ext_vector_type(4))) float f32x4;
typedef unsigned short u16;
typedef unsigned int u32;

#define GLOAD16(g, l)                                                          \
  __builtin_amdgcn_global_load_lds((const __attribute__((address_space(1))) u32*)(g), \
                                   (__attribute__((address_space(3))) u32*)(l), 16, 0, 0)

// ---------------- kernel 1: closed-form Cayley -> p,q vectors ----------------
// S = r 1^T - 1 r^T (rank 2). rotation = I - A T B, core = diag(d) + p 1^T + q r^T.
__global__ __launch_bounds__(512) void prep_kernel(const float* __restrict__ r,
                                                   const float* __restrict__ d,
                                                   float* __restrict__ pq) {
  int t = threadIdx.x;
  float rv = r[t], dv = d[t];
  float s1 = rv, s2 = rv * rv;
#pragma unroll
  for (int off = 32; off; off >>= 1) {
    s1 += __shfl_down(s1, off);
    s2 += __shfl_down(s2, off);
  }
  __shared__ float a1[8], a2[8];
  if ((t & 63) == 0) { a1[t >> 6] = s1; a2[t >> 6] = s2; }
  __syncthreads();
  float S1 = 0.f, S2 = 0.f;
#pragma unroll
  for (int w = 0; w < 8; ++w) { S1 += a1[w]; S2 += a2[w]; }
  float delta = 1.f - S1 * S1 + 512.f * S2;  // no cancellation: n*s2 dominates, >0
  float c = 2.f / delta;
  pq[t]       = c * dv * ((1.f + S1) * rv - S2);
  pq[512 + t] = -c * dv * (512.f * rv + 1.f - S1);
}

// ---------------- kernel 2: assemble lifted, emit bf16 hi/lo, GEMM-tile-swizzled ----
// lifted[i,j] = sum_{o=olo..ohi} rot_{o&3}[i-o, j-o],
//   rot0[a,b]=core[a,b], rot1[a,b]=core[b,511-a], rot2=core[511-a,511-b], rot3=core[511-b,a]
// Storage layout (per 128x64 tile, nb=i>>7, kt=j>>6):
//   elem = (nb*16+kt)*8192 + (i&127)*64 + ((j&63) ^ ((i&7)<<3))   [XOR-swizzle, G4/T2]
__global__ __launch_bounds__(256) void build_lifted(const float* __restrict__ rg,
                                                    const float* __restrict__ dg,
                                                    const float* __restrict__ pq,
                                                    u16* __restrict__ Lhi,
                                                    u16* __restrict__ Llo) {
  __shared__ float r[512], d[512], p[512], q[512];
  int t = threadIdx.x;
  for (int k = t; k < 512; k += 256) {
    r[k] = rg[k]; d[k] = dg[k]; p[k] = pq[k]; q[k] = pq[512 + k];
  }
  __syncthreads();
  const int i = blockIdx.x >> 2;
  const int j = ((blockIdx.x & 3) << 8) | t;
  const int olo = max(0, max(i, j) - 511);
  const int ohi = min(min(i, j), 512);
  float val = 0.f;
  for (int o = olo + ((0 - olo) & 3); o <= ohi; o += 4) {  // rot0
    int a = i - o; val += p[a] + q[a] * r[j - o];
  }
  for (int o = olo + ((1 - olo) & 3); o <= ohi; o += 4) {  // rot1
    int a = j - o; val += p[a] + q[a] * r[511 - i + o];
  }
  for (int o = olo + ((2 - olo) & 3); o <= ohi; o += 4) {  // rot2
    int a = 511 - i + o; val += p[a] + q[a] * r[511 - j + o];
  }
  for (int o = olo + ((3 - olo) & 3); o <= ohi; o += 4) {  // rot3
    int a = 511 - j + o; val += p[a] + q[a] * r[i - o];
  }
  // diagonal (d) contributions
  if (i == j) {
    for (int o = olo + ((0 - olo) & 3); o <= ohi; o += 4) val += d[i - o];
    for (int o = olo + ((2 - olo) & 3); o <= ohi; o += 4) val += d[511 - i + o];
  } else if ((i + j) & 1) {           // i+j odd -> i+j-511 even -> single anti-diag hit
    int os = (i + j - 511) >> 1;      // exact (even)
    if (os >= olo && os <= ohi && (os & 1)) {
      int idx = ((os & 3) == 1) ? ((511 + j - i) >> 1) : ((511 + i - j) >> 1);
      val += d[idx];
    }
  }
  // bf16 hi/lo split
  __hip_bfloat16 h = __float2bfloat16(val);
  float hf = __bfloat162float(h);
  __hip_bfloat16 l = __float2bfloat16(val - hf);
  size_t idx = ((size_t)((i >> 7) * 16 + (j >> 6)) << 13) + (size_t)((i & 127) << 6) +
               (size_t)((j & 63) ^ ((i & 7) << 3));
  union { __hip_bfloat16 b; u16 u; } ch, cl;
  ch.b = h; cl.b = l;
  Lhi[idx] = ch.u; Llo[idx] = cl.u;
}

// ---------------- kernel 3: y = x @ lifted^T, bf16 3-product split GEMM ------------
// 128x128 tile, BK=64, 4 waves (2x2), 4x4 16x16x32 frags/wave, 3 MFMA per frag pair.
__global__ __launch_bounds__(256, 2) void gemm_kernel(const float* __restrict__ x,
                                                      const u16* __restrict__ Bhg,
                                                      const u16* __restrict__ Blg,
                                                      float* __restrict__ out) {
  __shared__ u16 Ah[8192], Al[8192], Bh[8192], Bl[8192];  // 64 KB
  const int tid = threadIdx.x;
  const int nb = blockIdx.x & 7;        // n-column pinned per XCD (bid%8 round-robin)
  const int mb = blockIdx.x >> 3;
  const int m0 = mb << 7;
  const int n0 = nb << 7;
  const int lane = tid & 63;
  const int wave = tid >> 6;
  const int wm = wave >> 1, wn = wave & 1;
  const int lr = lane & 15, lg = lane >> 4;
  const int sel = (lr & 7) << 3;        // frag-read swizzle (row&7 == lr&7)

  // A staging geometry: per cc, row = cc*16 + (tid>>4), col = (tid&15)*4
  const int srow = tid >> 4;
  const int scol = (tid & 15) << 2;
  const int sidx0 = (srow << 6) + (scol ^ ((srow & 7) << 3));
  const float* xbase = x + (size_t)(m0 + srow) * 1024 + scol;

  f32x4 acc[4][4] = {};
  int baseA[4], baseB[4];
#pragma unroll
  for (int f = 0; f < 4; ++f) {
    baseA[f] = ((wm << 6) + (f << 4) + lr) << 6;
    baseB[f] = ((wn << 6) + (f << 4) + lr) << 6;
  }
  const u16* tBh = Bhg + ((size_t)nb << 17);
  const u16* tBl = Blg + ((size_t)nb << 17);

  for (int kt = 0; kt < 16; ++kt) {
    __syncthreads();
    // B: async global->LDS, linear 16 KB each (storage is pre-swizzled)
    {
      const u16* gh = tBh + (kt << 13) + (tid << 3);
      const u16* gl = tBl + (kt << 13) + (tid << 3);
#pragma unroll
      for (int c = 0; c < 4; ++c) {
        GLOAD16(gh + (c << 11), &Bh[(tid << 3) + (c << 11)]);
        GLOAD16(gl + (c << 11), &Bl[(tid << 3) + (c << 11)]);
      }
    }
    // A: fp32 global -> regs
    float4 av[8];
    const float* xp = xbase + (kt << 6);
#pragma unroll
    for (int cc = 0; cc < 8; ++cc)
      av[cc] = *reinterpret_cast<const float4*>(xp + (size_t)cc * 16 * 1024);
    // split to bf16 hi/lo, swizzled ds_write
#pragma unroll
    for (int cc = 0; cc < 8; ++cc) {
      float4 v = av[cc];
      __hip_bfloat162 h01 = __float22bfloat162_rn(make_float2(v.x, v.y));
      __hip_bfloat162 h23 = __float22bfloat162_rn(make_float2(v.z, v.w));
      float l0 = v.x - __bfloat162float(h01.x);
      float l1 = v.y - __bfloat162float(h01.y);
      float l2 = v.z - __bfloat162float(h23.x);
      float l3 = v.w - __bfloat162float(h23.y);
      __hip_bfloat162 m01 = __float22bfloat162_rn(make_float2(l0, l1));
      __hip_bfloat162 m23 = __float22bfloat162_rn(make_float2(l2, l3));
      union { __hip_bfloat162 h; u32 u; } uh0, uh1, ul0, ul1;
      uh0.h = h01; uh1.h = h23; ul0.h = m01; ul1.h = m23;
      int widx = sidx0 + (cc << 10);
      *reinterpret_cast<uint2*>(&Ah[widx]) = make_uint2(uh0.u, uh1.u);
      *reinterpret_cast<uint2*>(&Al[widx]) = make_uint2(ul0.u, ul1.u);
    }
    __syncthreads();
    // compute: 2 k-slices x 16 frag-pairs x 3 products = 96 MFMA
#pragma unroll
    for (int ks = 0; ks < 2; ++ks) {
      const int co = ((ks << 5) + (lg << 3)) ^ sel;
      sh8 ah[4], al[4], bh[4], bl[4];
#pragma unroll
      for (int f = 0; f < 4; ++f) {
        ah[f] = *reinterpret_cast<const sh8*>(&Ah[baseA[f] + co]);
        al[f] = *reinterpret_cast<const sh8*>(&Al[baseA[f] + co]);
        bh[f] = *reinterpret_cast<const sh8*>(&Bh[baseB[f] + co]);
        bl[f] = *reinterpret_cast<const sh8*>(&Bl[baseB[f] + co]);
      }
#pragma unroll
      for (int fm = 0; fm < 4; ++fm)
#pragma unroll
        for (int fn = 0; fn < 4; ++fn) {
          acc[fm][fn] = __builtin_amdgcn_mfma_f32_16x16x32_bf16(ah[fm], bh[fn], acc[fm][fn], 0, 0, 0);
          acc[fm][fn] = __builtin_amdgcn_mfma_f32_16x16x32_bf16(ah[fm], bl[fn], acc[fm][fn], 0, 0, 0);
          acc[fm][fn] = __builtin_amdgcn_mfma_f32_16x16x32_bf16(al[fm], bh[fn], acc[fm][fn], 0, 0, 0);
        }
    }
  }
  // epilogue: C/D layout col = lane&15, row = (lane>>4)*4 + reg
#pragma unroll
  for (int fm = 0; fm < 4; ++fm) {
    int row = m0 + (wm << 6) + (fm << 4) + (lg << 2);
#pragma unroll
    for (int fn = 0; fn < 4; ++fn) {
      int col = n0 + (wn << 6) + (fn << 4) + lr;
      float* op = out + (size_t)row * 1024 + col;
#pragma unroll
      for (int rr = 0; rr < 4; ++rr) op[(size_t)rr * 1024] = acc[fm][fn][rr];
    }
  }
}

// ---------------- launch ----------------
extern "C" void kernel_launch(void* const* d_in, const int* in_sizes, int n_in,
                              void* d_out, int out_size, void* d_ws, size_t ws_size,
                              hipStream_t stream) {
  (void)in_sizes; (void)n_in; (void)out_size; (void)ws_size;
  const float* x  = (const float*)d_in[0];
  const float* r  = (const float*)d_in[1];
  const float* dg = (const float*)d_in[2];
  float* out = (float*)d_out;
  float* pq = (float*)d_ws;                         // 2 * 512 f32 = 4 KB
  u16* Lhi = (u16*)((char*)d_ws + 4096);            // 2 MB, tile-swizzled
  u16* Llo = Lhi + 1024 * 1024;                     // 2 MB

  prep_kernel<<<1, 512, 0, stream>>>(r, dg, pq);
  build_lifted<<<4096, 256, 0, stream>>>(r, dg, pq, Lhi, Llo);
  gemm_kernel<<<4096, 256, 0, stream>>>(x, Lhi, Llo, out);
}

// Round 5
// 663.106 us; speedup vs baseline: 1.1598x; 1.1598x over previous
//
#include <hip/hip_runtime.h>
#include <hip/hip_bf16.h>
#include <hip/hip_fp16.h>

typedef __attribute__((ext_vector_type(8))) _Float16 h8;
typedef __attribute__((ext_vector_type(4))) float f32x4;
typedef unsigned short u16;
typedef unsigned int u32;

#define GLOAD16(g, l)                                                          \
  __builtin_amdgcn_global_load_lds((const __attribute__((address_space(1))) u32*)(g), \
                                   (__attribute__((address_space(3))) u32*)(l), 16, 0, 0)

// ---------------- kernel 1: closed-form Cayley -> p,q vectors ----------------
// S = r 1^T - 1 r^T (rank 2). rotation = I - A T B, core = diag(d) + p 1^T + q r^T.
__global__ __launch_bounds__(512) void prep_kernel(const float* __restrict__ r,
                                                   const float* __restrict__ d,
                                                   float* __restrict__ pq) {
  int t = threadIdx.x;
  float rv = r[t], dv = d[t];
  float s1 = rv, s2 = rv * rv;
#pragma unroll
  for (int off = 32; off; off >>= 1) {
    s1 += __shfl_down(s1, off);
    s2 += __shfl_down(s2, off);
  }
  __shared__ float a1[8], a2[8];
  if ((t & 63) == 0) { a1[t >> 6] = s1; a2[t >> 6] = s2; }
  __syncthreads();
  float S1 = 0.f, S2 = 0.f;
#pragma unroll
  for (int w = 0; w < 8; ++w) { S1 += a1[w]; S2 += a2[w]; }
  float delta = 1.f - S1 * S1 + 512.f * S2;  // no cancellation: n*s2 dominates, >0
  float c = 2.f / delta;
  pq[t]       = c * dv * ((1.f + S1) * rv - S2);
  pq[512 + t] = -c * dv * (512.f * rv + 1.f - S1);
}

// ---------------- kernel 2: lifted via per-diagonal prefix sums -------------------
// lifted[i,j], j-i = delta fixed per block. Each rotated-core term is a range-sum
// (residue class mod 4) of one of: p[a], d[a], C_d[a]=q[a]r[a+d], C_-d, D_{511+d}[a]
// = q[a]r[511+d-a], D_{511-d}. Prefix-by-4 in LDS -> O(1) per element.
// Emits fp16 hi/lo. Storage (per 128x64 tile): elem = ((i>>7)*16 + (j>>6))*8192
//                                        + (i&127)*64 + ((j&63) ^ ((i&7)<<3))
__global__ __launch_bounds__(256) void build_lifted_diag(const float* __restrict__ rg,
                                                         const float* __restrict__ dg,
                                                         const float* __restrict__ pq,
                                                         u16* __restrict__ Lhi,
                                                         u16* __restrict__ Llo) {
  __shared__ float r_s[512], d_s[512];
  __shared__ float W[6][512];  // Pp, Pd, CP, CM, DP, DM (prefix-by-residue-4)
  const int t = threadIdx.x;
  const int delta = (int)blockIdx.x - 1023;  // [-1023, 1023]
#pragma unroll
  for (int u = 0; u < 2; ++u) {
    int a = t + (u << 8);
    r_s[a] = rg[a];
    d_s[a] = dg[a];
    W[0][a] = pq[a];  // p
  }
  __syncthreads();
#pragma unroll
  for (int u = 0; u < 2; ++u) {
    int a = t + (u << 8);
    float qa = pq[512 + a];
    W[1][a] = d_s[a];
    int ap = a + delta, am = a - delta;
    int bp = 511 + delta - a, bm = 511 - delta - a;
    W[2][a] = ((unsigned)ap < 512u) ? qa * r_s[ap] : 0.f;
    W[3][a] = ((unsigned)am < 512u) ? qa * r_s[am] : 0.f;
    W[4][a] = ((unsigned)bp < 512u) ? qa * r_s[bp] : 0.f;
    W[5][a] = ((unsigned)bm < 512u) ? qa * r_s[bm] : 0.f;
  }
  __syncthreads();
  // Hillis-Steele prefix within each residue class mod 4, all 6 arrays at once.
  float* Wf = &W[0][0];
  for (int s = 4; s <= 256; s <<= 1) {
    float tmp[12];
#pragma unroll
    for (int u = 0; u < 12; ++u) {
      int idx = t + (u << 8);
      tmp[u] = ((idx & 511) >= s) ? Wf[idx - s] : 0.f;
    }
    __syncthreads();
#pragma unroll
    for (int u = 0; u < 12; ++u) Wf[t + (u << 8)] += tmp[u];
    __syncthreads();
  }
  const float* Pp = W[0]; const float* Pd = W[1];
  const float* CP = W[2]; const float* CM = W[3];
  const float* DP = W[4]; const float* DM = W[5];
  const int imin = max(0, -delta), imax = min(1023, 1023 - delta);
  for (int i = imin + t; i <= imax; i += 256) {
    const int j = i + delta;
    const int olo = max(0, max(i, j) - 511);
    const int ohi = min(min(i, j), 512);
    float val = 0.f;
    {  // rot0: a = i-o, o#0 mod 4 ; term p[a] + q[a]r[a+delta] (+d[a] if i==j)
      int oc = olo + ((0 - olo) & 3);
      if (oc <= ohi) {
        int ohc = ohi - ((ohi - oc) & 3);
        int alo = i - ohc, ahi = i - oc;
        val += Pp[ahi] + CP[ahi];
        if (alo >= 4) val -= Pp[alo - 4] + CP[alo - 4];
        if (delta == 0) { val += Pd[ahi]; if (alo >= 4) val -= Pd[alo - 4]; }
      }
    }
    {  // rot1: a = j-o, o#1 ; term p[a] + q[a]r[511+delta-a]
      int oc = olo + ((1 - olo) & 3);
      if (oc <= ohi) {
        int ohc = ohi - ((ohi - oc) & 3);
        int alo = j - ohc, ahi = j - oc;
        val += Pp[ahi] + DP[ahi];
        if (alo >= 4) val -= Pp[alo - 4] + DP[alo - 4];
      }
    }
    {  // rot2: a = 511-i+o, o#2 ; term p[a] + q[a]r[a-delta] (+d[a] if i==j)
      int oc = olo + ((2 - olo) & 3);
      if (oc <= ohi) {
        int ohc = ohi - ((ohi - oc) & 3);
        int alo = 511 - i + oc, ahi = 511 - i + ohc;
        val += Pp[ahi] + CM[ahi];
        if (alo >= 4) val -= Pp[alo - 4] + CM[alo - 4];
        if (delta == 0) { val += Pd[ahi]; if (alo >= 4) val -= Pd[alo - 4]; }
      }
    }
    {  // rot3: a = 511-j+o, o#3 ; term p[a] + q[a]r[511-delta-a]
      int oc = olo + ((3 - olo) & 3);
      if (oc <= ohi) {
        int ohc = ohi - ((ohi - oc) & 3);
        int alo = 511 - j + oc, ahi = 511 - j + ohc;
        val += Pp[ahi] + DM[ahi];
        if (alo >= 4) val -= Pp[alo - 4] + DM[alo - 4];
      }
    }
    if (delta & 1) {  // single possible core-diagonal hit via rot1/rot3
      int os = (i + j - 511) >> 1;  // i+j-511 even here
      if (os >= olo && os <= ohi) {
        int c = os & 3;
        if (c == 1) val += d_s[j - os];
        else if (c == 3) val += d_s[i - os];
      }
    }
    __half h = __float2half(val);
    float hf = __half2float(h);
    __half l = __float2half(val - hf);
    size_t idx = ((size_t)((i >> 7) * 16 + (j >> 6)) << 13) +
                 (size_t)((i & 127) << 6) + (size_t)((j & 63) ^ ((i & 7) << 3));
    Lhi[idx] = __half_as_ushort(h);
    Llo[idx] = __half_as_ushort(l);
  }
}

// ---------------- kernel 3: y = x @ lifted^T, fp16 2-product split GEMM ------------
// Round-1-validated structure (128x128 tile, BK=64, 4 waves 2x2, 4x4 16x16x32 frags,
// nb = bid&7 mapping); fp16 instead of bf16: y = fp16(x)*(Lh + Ll),
// fp16(x): 2^-11 rel; Lh+Ll: 2^-22 rel. 2 MFMA per frag pair, LDS 48 KB -> 3 blk/CU.
__global__ __launch_bounds__(256, 3) void gemm_kernel(const float* __restrict__ x,
                                                      const u16* __restrict__ Bhg,
                                                      const u16* __restrict__ Blg,
                                                      float* __restrict__ out) {
  __shared__ u16 Ah[8192], Bh[8192], Bl[8192];  // 48 KB
  const int tid = threadIdx.x;
  const int nb = blockIdx.x & 7;        // n-column pinned per XCD (round-1 mapping)
  const int mb = blockIdx.x >> 3;
  const int m0 = mb << 7;
  const int n0 = nb << 7;
  const int lane = tid & 63;
  const int wave = tid >> 6;
  const int wm = wave >> 1, wn = wave & 1;
  const int lr = lane & 15, lg = lane >> 4;
  const int sel = (lr & 7) << 3;        // frag-read swizzle (row&7 == lr&7)

  // A staging geometry: per cc, row = cc*16 + (tid>>4), col = (tid&15)*4
  const int srow = tid >> 4;
  const int scol = (tid & 15) << 2;
  const int sidx0 = (srow << 6) + (scol ^ ((srow & 7) << 3));
  const float* xbase = x + (size_t)(m0 + srow) * 1024 + scol;

  f32x4 acc[4][4] = {};
  int baseA[4], baseB[4];
#pragma unroll
  for (int f = 0; f < 4; ++f) {
    baseA[f] = ((wm << 6) + (f << 4) + lr) << 6;
    baseB[f] = ((wn << 6) + (f << 4) + lr) << 6;
  }
  const u16* tBh = Bhg + ((size_t)nb << 17);
  const u16* tBl = Blg + ((size_t)nb << 17);

  for (int kt = 0; kt < 16; ++kt) {
    __syncthreads();
    // B: async global->LDS, linear (storage is pre-swizzled)
    {
      const u16* gh = tBh + (kt << 13) + (tid << 3);
      const u16* gl = tBl + (kt << 13) + (tid << 3);
#pragma unroll
      for (int c = 0; c < 4; ++c) {
        GLOAD16(gh + (c << 11), &Bh[(tid << 3) + (c << 11)]);
        GLOAD16(gl + (c << 11), &Bl[(tid << 3) + (c << 11)]);
      }
    }
    // A: fp32 global -> regs -> fp16 -> swizzled ds_write
    float4 av[8];
    const float* xp = xbase + (kt << 6);
#pragma unroll
    for (int cc = 0; cc < 8; ++cc)
      av[cc] = *reinterpret_cast<const float4*>(xp + (size_t)cc * 16 * 1024);
#pragma unroll
    for (int cc = 0; cc < 8; ++cc) {
      float4 v = av[cc];
      union { __half2 h2[2]; uint2 u; } pk;
      pk.h2[0] = __floats2half2_rn(v.x, v.y);
      pk.h2[1] = __floats2half2_rn(v.z, v.w);
      *reinterpret_cast<uint2*>(&Ah[sidx0 + (cc << 10)]) = pk.u;
    }
    __syncthreads();
    // compute: 2 k-slices x 16 frag-pairs x 2 products = 64 MFMA
#pragma unroll
    for (int ks = 0; ks < 2; ++ks) {
      const int co = ((ks << 5) + (lg << 3)) ^ sel;
      h8 ah[4], bh[4], bl[4];
#pragma unroll
      for (int f = 0; f < 4; ++f) {
        ah[f] = *reinterpret_cast<const h8*>(&Ah[baseA[f] + co]);
        bh[f] = *reinterpret_cast<const h8*>(&Bh[baseB[f] + co]);
        bl[f] = *reinterpret_cast<const h8*>(&Bl[baseB[f] + co]);
      }
#pragma unroll
      for (int fm = 0; fm < 4; ++fm)
#pragma unroll
        for (int fn = 0; fn < 4; ++fn) {
          acc[fm][fn] = __builtin_amdgcn_mfma_f32_16x16x32_f16(ah[fm], bh[fn], acc[fm][fn], 0, 0, 0);
          acc[fm][fn] = __builtin_amdgcn_mfma_f32_16x16x32_f16(ah[fm], bl[fn], acc[fm][fn], 0, 0, 0);
        }
    }
  }
  // epilogue: C/D layout col = lane&15, row = (lane>>4)*4 + reg
#pragma unroll
  for (int fm = 0; fm < 4; ++fm) {
    int row = m0 + (wm << 6) + (fm << 4) + (lg << 2);
#pragma unroll
    for (int fn = 0; fn < 4; ++fn) {
      int col = n0 + (wn << 6) + (fn << 4) + lr;
      float* op = out + (size_t)row * 1024 + col;
#pragma unroll
      for (int rr = 0; rr < 4; ++rr) op[(size_t)rr * 1024] = acc[fm][fn][rr];
    }
  }
}

// ---------------- launch ----------------
extern "C" void kernel_launch(void* const* d_in, const int* in_sizes, int n_in,
                              void* d_out, int out_size, void* d_ws, size_t ws_size,
                              hipStream_t stream) {
  (void)in_sizes; (void)n_in; (void)out_size; (void)ws_size;
  const float* x  = (const float*)d_in[0];
  const float* r  = (const float*)d_in[1];
  const float* dg = (const float*)d_in[2];
  float* out = (float*)d_out;
  float* pq = (float*)d_ws;                         // 2 * 512 f32 = 4 KB
  u16* Lhi = (u16*)((char*)d_ws + 4096);            // 2 MB, tile-swizzled fp16
  u16* Llo = Lhi + 1024 * 1024;                     // 2 MB

  prep_kernel<<<1, 512, 0, stream>>>(r, dg, pq);
  build_lifted_diag<<<2047, 256, 0, stream>>>(r, dg, pq, Lhi, Llo);
  gemm_kernel<<<4096, 256, 0, stream>>>(x, Lhi, Llo, out);
}